// Round 3
// baseline (122.416 us; speedup 1.0000x reference)
//
#include <hip/hip_runtime.h>

#define BB 4
#define CC 512    // C_CTX
#define TDIM 512  // T
#define HH 128
#define TT 8      // t-rows per block
#define CH 256    // c-half handled per score block

// ---------------- prep: key/query/value projections (f32 to ws) -------------
__global__ __launch_bounds__(128) void prep_kernel(
    const float* __restrict__ ctx_x, const float* __restrict__ ctx_y,
    const float* __restrict__ tgt_x,
    const float* __restrict__ W_in, const float* __restrict__ b_in,
    const float* __restrict__ W_ctx, const float* __restrict__ b_ctx,
    float* __restrict__ key, float* __restrict__ query, float* __restrict__ value)
{
    int row = blockIdx.x;     // b*512 + r
    int h   = threadIdx.x;    // 0..127

    float4 cx = ((const float4*)ctx_x)[row];
    float2 cy = ((const float2*)ctx_y)[row];
    float4 tx = ((const float4*)tgt_x)[row];

    float wi0 = W_in[0*HH+h], wi1 = W_in[1*HH+h], wi2 = W_in[2*HH+h];
    float wi3 = W_in[3*HH+h], wi4 = W_in[4*HH+h];
    float wc0 = W_ctx[0*HH+h], wc1 = W_ctx[1*HH+h], wc2 = W_ctx[2*HH+h];
    float bi  = b_in[h], bc = b_ctx[h];

    value[row*HH+h] = fmaf(cx.x,wi0, fmaf(cx.y,wi1, fmaf(cx.z,wi2, fmaf(cy.x,wi3, fmaf(cy.y,wi4, bi)))));
    key  [row*HH+h] = fmaf(cx.x,wc0, fmaf(cx.y,wc1, fmaf(cx.z,wc2, bc)));
    query[row*HH+h] = fmaf(tx.x,wc0, fmaf(tx.y,wc1, fmaf(tx.z,wc2, bc)));
}

// ------------- main: scores + local softmax + PV partial (per c-half) -------
__global__ __launch_bounds__(256) void score_pv_kernel(
    const float* __restrict__ key, const float* __restrict__ query,
    const float* __restrict__ value,
    float* __restrict__ repp, float* __restrict__ ml)
{
    const int bx   = blockIdx.x;      // 0..511
    const int b    = bx >> 7;
    const int rem  = bx & 127;
    const int tb   = rem >> 1;
    const int half = rem & 1;
    const int t0   = tb * TT;
    const int c0   = half * CH;
    const int tid  = threadIdx.x;

    __shared__ float q[TT][HH];            // 4 KB
    __shared__ float s[TT][CH];            // 8 KB raw scores
    __shared__ float pT[CH][TT];           // 8 KB unnormalized exp, transposed
    __shared__ float partial[2][TT][HH];   // 8 KB

    // --- q tile to LDS ---
    for (int i = tid; i < TT*HH; i += 256) {
        q[i>>7][i&127] = query[(b*TDIM + t0 + (i>>7))*HH + (i&127)];
    }
    __syncthreads();

    // --- scores: thread = (c-pair, h-quad). Per load instr, the 4 hq lanes
    //     cover one contiguous 64B chunk of a k row (coalesced). q LDS reads
    //     are amortized over the c-pair; partials combined via shfl_xor. ---
    const int cp = tid >> 2;   // 0..63
    const int hq = tid & 3;    // 0..3
    for (int pass = 0; pass < 2; ++pass) {
        const int c1 = c0 + pass*128 + 2*cp;
        const float* k1 = &key[(b*CC + c1)*HH];
        const float* k2 = k1 + HH;
        float acc0[TT], acc1[TT];
        #pragma unroll
        for (int t = 0; t < TT; ++t) { acc0[t] = 0.f; acc1[t] = 0.f; }
        #pragma unroll
        for (int i = 0; i < 8; ++i) {
            const int hb = i*16 + hq*4;
            float4 ka = *(const float4*)(k1 + hb);
            float4 kb = *(const float4*)(k2 + hb);
            #pragma unroll
            for (int t = 0; t < TT; ++t) {
                float4 qv = *(const float4*)(&q[t][hb]);
                acc0[t] += fabsf(ka.x-qv.x)+fabsf(ka.y-qv.y)+fabsf(ka.z-qv.z)+fabsf(ka.w-qv.w);
                acc1[t] += fabsf(kb.x-qv.x)+fabsf(kb.y-qv.y)+fabsf(kb.z-qv.z)+fabsf(kb.w-qv.w);
            }
        }
        #pragma unroll
        for (int t = 0; t < TT; ++t) {
            float v0 = acc0[t], v1 = acc1[t];
            v0 += __shfl_xor(v0, 1); v0 += __shfl_xor(v0, 2);
            v1 += __shfl_xor(v1, 1); v1 += __shfl_xor(v1, 2);
            if (hq == 0) {
                s[t][pass*128 + 2*cp]     = -0.5f * v0;
                s[t][pass*128 + 2*cp + 1] = -0.5f * v1;
            }
        }
    }
    __syncthreads();

    // --- local softmax stats over this c-half (wave per 2 t-rows) ---
    {
        const int wave = tid >> 6, lane = tid & 63;
        #pragma unroll
        for (int tw = 0; tw < 2; ++tw) {
            const int t = wave*2 + tw;
            float x0 = s[t][lane], x1 = s[t][lane+64], x2 = s[t][lane+128], x3 = s[t][lane+192];
            float m = fmaxf(fmaxf(x0, x1), fmaxf(x2, x3));
            #pragma unroll
            for (int msk = 32; msk; msk >>= 1) m = fmaxf(m, __shfl_xor(m, msk));
            float e0 = __expf(x0-m), e1 = __expf(x1-m), e2 = __expf(x2-m), e3 = __expf(x3-m);
            float sum = e0 + e1 + e2 + e3;
            #pragma unroll
            for (int msk = 32; msk; msk >>= 1) sum += __shfl_xor(sum, msk);
            pT[lane    ][t] = e0;
            pT[lane+ 64][t] = e1;
            pT[lane+128][t] = e2;
            pT[lane+192][t] = e3;
            if (lane == 0) { ml[bx*16 + t] = m; ml[bx*16 + 8 + t] = sum; }
        }
    }
    __syncthreads();

    // --- PV partial: rep_half[t][h] = sum_c pT[c][t] * value[c0+c][h] ---
    {
        const int g = tid >> 7, h = tid & 127;
        float r[TT];
        #pragma unroll
        for (int t = 0; t < TT; ++t) r[t] = 0.f;
        for (int c = g*128; c < g*128 + 128; ++c) {
            float v = value[(b*CC + c0 + c)*HH + h];
            float4 w0 = *(const float4*)&pT[c][0];
            float4 w1 = *(const float4*)&pT[c][4];
            r[0] = fmaf(w0.x, v, r[0]);
            r[1] = fmaf(w0.y, v, r[1]);
            r[2] = fmaf(w0.z, v, r[2]);
            r[3] = fmaf(w0.w, v, r[3]);
            r[4] = fmaf(w1.x, v, r[4]);
            r[5] = fmaf(w1.y, v, r[5]);
            r[6] = fmaf(w1.z, v, r[6]);
            r[7] = fmaf(w1.w, v, r[7]);
        }
        #pragma unroll
        for (int t = 0; t < TT; ++t) partial[g][t][h] = r[t];
    }
    __syncthreads();
    {
        const float* p0 = &partial[0][0][0];
        const float* p1 = &partial[1][0][0];
        for (int i = tid; i < TT*HH; i += 256)
            repp[bx*(TT*HH) + i] = p0[i] + p1[i];
    }
}

// ------------- combine halves + output projection ---------------------------
__global__ __launch_bounds__(256) void combine_proj_kernel(
    const float* __restrict__ repp, const float* __restrict__ ml,
    const float* __restrict__ W_tgt, const float* __restrict__ b_tgt,
    float* __restrict__ out)
{
    const int bx  = blockIdx.x;      // 0..255 = b*64 + tb
    const int b   = bx >> 6, tb = bx & 63;
    const int t0  = tb * TT;
    const int tid = threadIdx.x;
    const int blk0 = bx << 1;        // score-block ids for the two halves
    const int blk1 = blk0 + 1;

    __shared__ float rep[TT][HH];    // 4 KB
    __shared__ float cf[2][TT];

    if (tid < TT) {
        float m0 = ml[blk0*16 + tid], l0 = ml[blk0*16 + 8 + tid];
        float m1 = ml[blk1*16 + tid], l1 = ml[blk1*16 + 8 + tid];
        float M  = fmaxf(m0, m1);
        float a0 = __expf(m0 - M), a1 = __expf(m1 - M);
        float L  = fmaf(a0, l0, a1 * l1);
        cf[0][tid] = a0 / L;
        cf[1][tid] = a1 / L;
    }
    __syncthreads();
    for (int i = tid; i < TT*HH; i += 256) {
        int t = i >> 7;
        (&rep[0][0])[i] = cf[0][t]*repp[blk0*(TT*HH) + i] + cf[1][t]*repp[blk1*(TT*HH) + i];
    }
    __syncthreads();

    const int g = tid >> 7, h = tid & 127;   // g: t-quad
    float bt = b_tgt[h];
    float acc[4];
    #pragma unroll
    for (int i = 0; i < 4; ++i) acc[i] = bt;
    for (int k = 0; k < HH; k += 4) {
        float w0 = W_tgt[(k+0)*HH + h];
        float w1 = W_tgt[(k+1)*HH + h];
        float w2 = W_tgt[(k+2)*HH + h];
        float w3 = W_tgt[(k+3)*HH + h];
        #pragma unroll
        for (int i = 0; i < 4; ++i) {
            const float4 rv = *(const float4*)&rep[g*4 + i][k];
            acc[i] = fmaf(rv.x, w0, fmaf(rv.y, w1, fmaf(rv.z, w2, fmaf(rv.w, w3, acc[i]))));
        }
    }
    #pragma unroll
    for (int i = 0; i < 4; ++i)
        out[(b*TDIM + t0 + g*4 + i)*HH + h] = acc[i];
}

extern "C" void kernel_launch(void* const* d_in, const int* in_sizes, int n_in,
                              void* d_out, int out_size, void* d_ws, size_t ws_size,
                              hipStream_t stream) {
    const float* ctx_x = (const float*)d_in[0];
    const float* ctx_y = (const float*)d_in[1];
    const float* tgt_x = (const float*)d_in[2];
    const float* W_in  = (const float*)d_in[3];
    const float* b_in  = (const float*)d_in[4];
    const float* W_ctx = (const float*)d_in[5];
    const float* b_ctx = (const float*)d_in[6];
    const float* W_tgt = (const float*)d_in[7];
    const float* b_tgt = (const float*)d_in[8];

    float* ws    = (float*)d_ws;
    float* key   = ws;                      // 262144 f32
    float* query = ws + 1*BB*CC*HH;         // 262144
    float* value = ws + 2*BB*CC*HH;         // 262144
    float* repp  = ws + 3*BB*CC*HH;         // 512 blocks * 1024
    float* ml    = repp + 512*TT*HH;        // 512 blocks * 16

    prep_kernel<<<BB*CC, 128, 0, stream>>>(ctx_x, ctx_y, tgt_x,
                                           W_in, b_in, W_ctx, b_ctx,
                                           key, query, value);
    score_pv_kernel<<<BB*(TDIM/TT)*2, 256, 0, stream>>>(key, query, value, repp, ml);
    combine_proj_kernel<<<BB*(TDIM/TT), 256, 0, stream>>>(repp, ml, W_tgt, b_tgt,
                                                          (float*)d_out);
}

// Round 4
// 97.983 us; speedup vs baseline: 1.2494x; 1.2494x over previous
//
#include <hip/hip_runtime.h>

#define BB 4
#define CC 512    // C_CTX
#define TDIM 512  // T
#define HH 128
#define TT 8      // t-rows per tile
#define CH 128    // c-quarter per score block
#define NSPLIT 4  // c-splits per (b, t-tile)

// ---------------- prep: key/query/value projections (f32 to ws) -------------
__global__ __launch_bounds__(128) void prep_kernel(
    const float* __restrict__ ctx_x, const float* __restrict__ ctx_y,
    const float* __restrict__ tgt_x,
    const float* __restrict__ W_in, const float* __restrict__ b_in,
    const float* __restrict__ W_ctx, const float* __restrict__ b_ctx,
    float* __restrict__ key, float* __restrict__ query, float* __restrict__ value)
{
    int row = blockIdx.x;     // b*512 + r
    int h   = threadIdx.x;    // 0..127

    float4 cx = ((const float4*)ctx_x)[row];
    float2 cy = ((const float2*)ctx_y)[row];
    float4 tx = ((const float4*)tgt_x)[row];

    float wi0 = W_in[0*HH+h], wi1 = W_in[1*HH+h], wi2 = W_in[2*HH+h];
    float wi3 = W_in[3*HH+h], wi4 = W_in[4*HH+h];
    float wc0 = W_ctx[0*HH+h], wc1 = W_ctx[1*HH+h], wc2 = W_ctx[2*HH+h];
    float bi  = b_in[h], bc = b_ctx[h];

    value[row*HH+h] = fmaf(cx.x,wi0, fmaf(cx.y,wi1, fmaf(cx.z,wi2, fmaf(cy.x,wi3, fmaf(cy.y,wi4, bi)))));
    key  [row*HH+h] = fmaf(cx.x,wc0, fmaf(cx.y,wc1, fmaf(cx.z,wc2, bc)));
    query[row*HH+h] = fmaf(tx.x,wc0, fmaf(tx.y,wc1, fmaf(tx.z,wc2, bc)));
}

// ------------- main: scores + local softmax + PV partial (per c-quarter) ----
// grid = BB * (TDIM/TT) * NSPLIT = 1024 blocks, 256 threads, ~20KB LDS,
// VGPR capped at 128 -> 4 blocks/CU.
__global__ __launch_bounds__(256, 4) void score_pv_kernel(
    const float* __restrict__ key, const float* __restrict__ query,
    const float* __restrict__ value,
    float* __restrict__ repp, float* __restrict__ ml)
{
    const int bx      = blockIdx.x;          // b*256 + tb*4 + quarter
    const int b       = bx >> 8;
    const int tb      = (bx >> 2) & 63;
    const int quarter = bx & 3;
    const int t0      = tb * TT;
    const int c0      = quarter * CH;
    const int tid     = threadIdx.x;

    __shared__ float q[TT][HH];            // 4 KB
    __shared__ float s[TT][CH];            // 4 KB
    __shared__ float pT[CH][TT];           // 4 KB unnormalized exp, transposed
    __shared__ float partial[2][TT][HH];   // 8 KB

    // --- q tile to LDS ---
    for (int i = tid; i < TT*HH; i += 256)
        q[i>>7][i&127] = query[(b*TDIM + t0 + (i>>7))*HH + (i&127)];
    __syncthreads();

    // --- scores: thread = (c-pair cd, h-quad hq). Each thread covers its two
    //     c-rows over the 32 h-values {j*16 + hq*4 .. +3}. k live = 2 float4,
    //     acc = 16 f32 -> low pressure. q LDS reads amortized over the pair.
    const int cd = tid >> 2;   // 0..63
    const int hq = tid & 3;    // 0..3
    const float* k0p = &key[(b*CC + c0 + cd*2)*HH];
    const float* k1p = k0p + HH;
    float acc0[TT], acc1[TT];
    #pragma unroll
    for (int t = 0; t < TT; ++t) { acc0[t] = 0.f; acc1[t] = 0.f; }
    #pragma unroll
    for (int j = 0; j < 8; ++j) {
        const int hb = j*16 + hq*4;
        float4 ka = *(const float4*)(k0p + hb);
        float4 kb = *(const float4*)(k1p + hb);
        #pragma unroll
        for (int t = 0; t < TT; ++t) {
            float4 qv = *(const float4*)&q[t][hb];
            acc0[t] += fabsf(ka.x-qv.x)+fabsf(ka.y-qv.y)+fabsf(ka.z-qv.z)+fabsf(ka.w-qv.w);
            acc1[t] += fabsf(kb.x-qv.x)+fabsf(kb.y-qv.y)+fabsf(kb.z-qv.z)+fabsf(kb.w-qv.w);
        }
    }
    #pragma unroll
    for (int t = 0; t < TT; ++t) {
        float v0 = acc0[t], v1 = acc1[t];
        v0 += __shfl_xor(v0, 1); v0 += __shfl_xor(v0, 2);
        v1 += __shfl_xor(v1, 1); v1 += __shfl_xor(v1, 2);
        if (hq == 0) s[t][cd*2]     = -0.5f * v0;
        if (hq == 1) s[t][cd*2 + 1] = -0.5f * v1;
    }
    __syncthreads();

    // --- local softmax over this c-quarter (wave per 2 t-rows) ---
    {
        const int wave = tid >> 6, lane = tid & 63;
        #pragma unroll
        for (int tw = 0; tw < 2; ++tw) {
            const int t = wave*2 + tw;
            float x0 = s[t][lane], x1 = s[t][lane+64];
            float m = fmaxf(x0, x1);
            #pragma unroll
            for (int msk = 32; msk; msk >>= 1) m = fmaxf(m, __shfl_xor(m, msk));
            float e0 = __expf(x0-m), e1 = __expf(x1-m);
            float sum = e0 + e1;
            #pragma unroll
            for (int msk = 32; msk; msk >>= 1) sum += __shfl_xor(sum, msk);
            pT[lane   ][t] = e0;
            pT[lane+64][t] = e1;
            if (lane == 0) { ml[bx*16 + t] = m; ml[bx*16 + 8 + t] = sum; }
        }
    }
    __syncthreads();

    // --- PV partial: rep_q[t][h] = sum_c pT[c][t] * value[c0+c][h] ---
    {
        const int g = tid >> 7, h = tid & 127;
        float r[TT];
        #pragma unroll
        for (int t = 0; t < TT; ++t) r[t] = 0.f;
        for (int c = g*64; c < g*64 + 64; ++c) {
            float v = value[(b*CC + c0 + c)*HH + h];
            float4 w0 = *(const float4*)&pT[c][0];
            float4 w1 = *(const float4*)&pT[c][4];
            r[0] = fmaf(w0.x, v, r[0]);
            r[1] = fmaf(w0.y, v, r[1]);
            r[2] = fmaf(w0.z, v, r[2]);
            r[3] = fmaf(w0.w, v, r[3]);
            r[4] = fmaf(w1.x, v, r[4]);
            r[5] = fmaf(w1.y, v, r[5]);
            r[6] = fmaf(w1.z, v, r[6]);
            r[7] = fmaf(w1.w, v, r[7]);
        }
        #pragma unroll
        for (int t = 0; t < TT; ++t) partial[g][t][h] = r[t];
    }
    __syncthreads();
    {
        const float* p0 = &partial[0][0][0];
        const float* p1 = &partial[1][0][0];
        for (int i = tid; i < TT*HH; i += 256)
            repp[bx*(TT*HH) + i] = p0[i] + p1[i];
    }
}

// ------------- combine 4 quarters + output projection ------------------------
__global__ __launch_bounds__(256) void combine_proj_kernel(
    const float* __restrict__ repp, const float* __restrict__ ml,
    const float* __restrict__ W_tgt, const float* __restrict__ b_tgt,
    float* __restrict__ out)
{
    const int cx  = blockIdx.x;      // 0..255 = b*64 + tb
    const int b   = cx >> 6, tb = cx & 63;
    const int t0  = tb * TT;
    const int tid = threadIdx.x;

    __shared__ float rep[TT][HH];    // 4 KB
    __shared__ float cf[NSPLIT][TT];

    if (tid < TT) {
        float mj[NSPLIT], lj[NSPLIT], aj[NSPLIT];
        float M = -1e30f;
        #pragma unroll
        for (int j = 0; j < NSPLIT; ++j) {
            mj[j] = ml[(cx*NSPLIT + j)*16 + tid];
            lj[j] = ml[(cx*NSPLIT + j)*16 + 8 + tid];
            M = fmaxf(M, mj[j]);
        }
        float L = 0.f;
        #pragma unroll
        for (int j = 0; j < NSPLIT; ++j) { aj[j] = __expf(mj[j]-M); L = fmaf(aj[j], lj[j], L); }
        float invL = 1.f / L;
        #pragma unroll
        for (int j = 0; j < NSPLIT; ++j) cf[j][tid] = aj[j] * invL;
    }
    __syncthreads();
    for (int i = tid; i < TT*HH; i += 256) {
        const int t = i >> 7;
        float acc = 0.f;
        #pragma unroll
        for (int j = 0; j < NSPLIT; ++j)
            acc = fmaf(cf[j][t], repp[(cx*NSPLIT + j)*(TT*HH) + i], acc);
        (&rep[0][0])[i] = acc;
    }
    __syncthreads();

    const int g = tid >> 7, h = tid & 127;   // g: t-quad
    float bt = b_tgt[h];
    float acc[4];
    #pragma unroll
    for (int i = 0; i < 4; ++i) acc[i] = bt;
    for (int k = 0; k < HH; k += 4) {
        float w0 = W_tgt[(k+0)*HH + h];
        float w1 = W_tgt[(k+1)*HH + h];
        float w2 = W_tgt[(k+2)*HH + h];
        float w3 = W_tgt[(k+3)*HH + h];
        #pragma unroll
        for (int i = 0; i < 4; ++i) {
            const float4 rv = *(const float4*)&rep[g*4 + i][k];
            acc[i] = fmaf(rv.x, w0, fmaf(rv.y, w1, fmaf(rv.z, w2, fmaf(rv.w, w3, acc[i]))));
        }
    }
    #pragma unroll
    for (int i = 0; i < 4; ++i)
        out[(b*TDIM + t0 + g*4 + i)*HH + h] = acc[i];
}

extern "C" void kernel_launch(void* const* d_in, const int* in_sizes, int n_in,
                              void* d_out, int out_size, void* d_ws, size_t ws_size,
                              hipStream_t stream) {
    const float* ctx_x = (const float*)d_in[0];
    const float* ctx_y = (const float*)d_in[1];
    const float* tgt_x = (const float*)d_in[2];
    const float* W_in  = (const float*)d_in[3];
    const float* b_in  = (const float*)d_in[4];
    const float* W_ctx = (const float*)d_in[5];
    const float* b_ctx = (const float*)d_in[6];
    const float* W_tgt = (const float*)d_in[7];
    const float* b_tgt = (const float*)d_in[8];

    float* ws    = (float*)d_ws;
    float* key   = ws;                      // 262144 f32
    float* query = ws + 1*BB*CC*HH;         // 262144
    float* value = ws + 2*BB*CC*HH;         // 262144
    float* repp  = ws + 3*BB*CC*HH;         // 1024 blocks * 1024
    float* ml    = repp + 1024*TT*HH;       // 1024 blocks * 16

    prep_kernel<<<BB*CC, 128, 0, stream>>>(ctx_x, ctx_y, tgt_x,
                                           W_in, b_in, W_ctx, b_ctx,
                                           key, query, value);
    score_pv_kernel<<<BB*(TDIM/TT)*NSPLIT, 256, 0, stream>>>(key, query, value,
                                                             repp, ml);
    combine_proj_kernel<<<BB*(TDIM/TT), 256, 0, stream>>>(repp, ml, W_tgt, b_tgt,
                                                          (float*)d_out);
}

// Round 5
// 42.484 us; speedup vs baseline: 2.8814x; 2.3063x over previous
//
#include <hip/hip_runtime.h>

#define BB 4
#define CC 512    // C_CTX
#define TDIM 512  // T
#define HH 128
#define TT 8      // t-rows per tile
#define CH 256    // c-half per score block
#define NSPLIT 2  // c-splits per (b, t-tile)

// ---------------- prep: key/query/value projections (f32 to ws) -------------
__global__ __launch_bounds__(128) void prep_kernel(
    const float* __restrict__ ctx_x, const float* __restrict__ ctx_y,
    const float* __restrict__ tgt_x,
    const float* __restrict__ W_in, const float* __restrict__ b_in,
    const float* __restrict__ W_ctx, const float* __restrict__ b_ctx,
    float* __restrict__ key, float* __restrict__ query, float* __restrict__ value)
{
    int row = blockIdx.x;     // b*512 + r
    int h   = threadIdx.x;    // 0..127

    float4 cx = ((const float4*)ctx_x)[row];
    float2 cy = ((const float2*)ctx_y)[row];
    float4 tx = ((const float4*)tgt_x)[row];

    float wi0 = W_in[0*HH+h], wi1 = W_in[1*HH+h], wi2 = W_in[2*HH+h];
    float wi3 = W_in[3*HH+h], wi4 = W_in[4*HH+h];
    float wc0 = W_ctx[0*HH+h], wc1 = W_ctx[1*HH+h], wc2 = W_ctx[2*HH+h];
    float bi  = b_in[h], bc = b_ctx[h];

    value[row*HH+h] = fmaf(cx.x,wi0, fmaf(cx.y,wi1, fmaf(cx.z,wi2, fmaf(cy.x,wi3, fmaf(cy.y,wi4, bi)))));
    key  [row*HH+h] = fmaf(cx.x,wc0, fmaf(cx.y,wc1, fmaf(cx.z,wc2, bc)));
    query[row*HH+h] = fmaf(tx.x,wc0, fmaf(tx.y,wc1, fmaf(tx.z,wc2, bc)));
}

// ------------- main: scores + local softmax + PV partial (per c-half) -------
// grid = BB * (TDIM/TT) * NSPLIT = 512 blocks, 256 threads, 52 KB LDS.
// No min-waves clamp: score loop needs ~80 live VGPRs; 2 blocks/CU is enough.
__global__ __launch_bounds__(256) void score_pv_kernel(
    const float* __restrict__ key, const float* __restrict__ query,
    const float* __restrict__ value,
    float* __restrict__ repp, float* __restrict__ ml)
{
    const int bx   = blockIdx.x;          // b*128 + tb*2 + half
    const int b    = bx >> 7;
    const int tb   = (bx >> 1) & 63;
    const int half = bx & 1;
    const int t0   = tb * TT;
    const int c0   = half * CH;
    const int tid  = threadIdx.x;

    __shared__ float q[TT][HH];             // 4 KB
    __shared__ float s[TT][CH];             // 8 KB raw scores
    __shared__ float pT[CH][TT];            // 8 KB unnormalized exp, transposed
    __shared__ float partial[8][TT][HH];    // 32 KB PV partials

    // --- q tile to LDS ---
    for (int i = tid; i < TT*HH; i += 256)
        q[i>>7][i&127] = query[(b*TDIM + t0 + (i>>7))*HH + (i&127)];
    __syncthreads();

    // --- scores: thread = (c-quad cq, h-quad hq). 4 k-rows live; each q
    //     float4 LDS read amortized over 4 c-rows. acc 4x8, k 4x4 -> ~75 VGPR.
    {
        const int cq = tid >> 2;   // 0..63 -> rows c0+cq*4 .. +3
        const int hq = tid & 3;    // 0..3  -> h-slice j*16 + hq*4
        const float* kp = &key[(b*CC + c0 + cq*4)*HH];
        float a0[TT], a1[TT], a2[TT], a3[TT];
        #pragma unroll
        for (int t = 0; t < TT; ++t) { a0[t]=0.f; a1[t]=0.f; a2[t]=0.f; a3[t]=0.f; }
        #pragma unroll
        for (int j = 0; j < 8; ++j) {
            const int hb = j*16 + hq*4;
            float4 k0 = *(const float4*)(kp + 0*HH + hb);
            float4 k1 = *(const float4*)(kp + 1*HH + hb);
            float4 k2 = *(const float4*)(kp + 2*HH + hb);
            float4 k3 = *(const float4*)(kp + 3*HH + hb);
            #pragma unroll
            for (int t = 0; t < TT; ++t) {
                float4 qv = *(const float4*)&q[t][hb];
                a0[t] += fabsf(k0.x-qv.x)+fabsf(k0.y-qv.y)+fabsf(k0.z-qv.z)+fabsf(k0.w-qv.w);
                a1[t] += fabsf(k1.x-qv.x)+fabsf(k1.y-qv.y)+fabsf(k1.z-qv.z)+fabsf(k1.w-qv.w);
                a2[t] += fabsf(k2.x-qv.x)+fabsf(k2.y-qv.y)+fabsf(k2.z-qv.z)+fabsf(k2.w-qv.w);
                a3[t] += fabsf(k3.x-qv.x)+fabsf(k3.y-qv.y)+fabsf(k3.z-qv.z)+fabsf(k3.w-qv.w);
            }
        }
        #pragma unroll
        for (int t = 0; t < TT; ++t) {
            float v0=a0[t], v1=a1[t], v2=a2[t], v3=a3[t];
            v0 += __shfl_xor(v0,1); v0 += __shfl_xor(v0,2);
            v1 += __shfl_xor(v1,1); v1 += __shfl_xor(v1,2);
            v2 += __shfl_xor(v2,1); v2 += __shfl_xor(v2,2);
            v3 += __shfl_xor(v3,1); v3 += __shfl_xor(v3,2);
            if (hq == 0)
                *(float4*)&s[t][cq*4] =
                    make_float4(-0.5f*v0, -0.5f*v1, -0.5f*v2, -0.5f*v3);
        }
    }
    __syncthreads();

    // --- local softmax over this c-half (wave per 2 t-rows) ---
    {
        const int wave = tid >> 6, lane = tid & 63;
        #pragma unroll
        for (int tw = 0; tw < 2; ++tw) {
            const int t = wave*2 + tw;
            float x0 = s[t][lane], x1 = s[t][lane+64], x2 = s[t][lane+128], x3 = s[t][lane+192];
            float m = fmaxf(fmaxf(x0, x1), fmaxf(x2, x3));
            #pragma unroll
            for (int msk = 32; msk; msk >>= 1) m = fmaxf(m, __shfl_xor(m, msk));
            float e0 = __expf(x0-m), e1 = __expf(x1-m), e2 = __expf(x2-m), e3 = __expf(x3-m);
            float sum = e0 + e1 + e2 + e3;
            #pragma unroll
            for (int msk = 32; msk; msk >>= 1) sum += __shfl_xor(sum, msk);
            pT[lane    ][t] = e0;
            pT[lane+ 64][t] = e1;
            pT[lane+128][t] = e2;
            pT[lane+192][t] = e3;
            if (lane == 0) { ml[bx*16 + t] = m; ml[bx*16 + 8 + t] = sum; }
        }
    }
    __syncthreads();

    // --- PV partial: thread = (c-octant g, h-quad hs). value loads are
    //     float4 fully coalesced (2 rows x 512B per wave-instr). ---
    {
        const int g  = tid >> 5;   // 0..7 -> local c range g*32..+31
        const int hs = tid & 31;   // h = hs*4 .. +3
        float4 acc[TT];
        #pragma unroll
        for (int t = 0; t < TT; ++t) acc[t] = make_float4(0.f,0.f,0.f,0.f);
        const float* vp = &value[(b*CC + c0 + g*32)*HH + hs*4];
        #pragma unroll 4
        for (int c = 0; c < 32; ++c) {
            float4 vv = *(const float4*)(vp + c*HH);
            float4 p0 = *(const float4*)&pT[g*32 + c][0];
            float4 p1 = *(const float4*)&pT[g*32 + c][4];
            acc[0].x=fmaf(p0.x,vv.x,acc[0].x); acc[0].y=fmaf(p0.x,vv.y,acc[0].y);
            acc[0].z=fmaf(p0.x,vv.z,acc[0].z); acc[0].w=fmaf(p0.x,vv.w,acc[0].w);
            acc[1].x=fmaf(p0.y,vv.x,acc[1].x); acc[1].y=fmaf(p0.y,vv.y,acc[1].y);
            acc[1].z=fmaf(p0.y,vv.z,acc[1].z); acc[1].w=fmaf(p0.y,vv.w,acc[1].w);
            acc[2].x=fmaf(p0.z,vv.x,acc[2].x); acc[2].y=fmaf(p0.z,vv.y,acc[2].y);
            acc[2].z=fmaf(p0.z,vv.z,acc[2].z); acc[2].w=fmaf(p0.z,vv.w,acc[2].w);
            acc[3].x=fmaf(p0.w,vv.x,acc[3].x); acc[3].y=fmaf(p0.w,vv.y,acc[3].y);
            acc[3].z=fmaf(p0.w,vv.z,acc[3].z); acc[3].w=fmaf(p0.w,vv.w,acc[3].w);
            acc[4].x=fmaf(p1.x,vv.x,acc[4].x); acc[4].y=fmaf(p1.x,vv.y,acc[4].y);
            acc[4].z=fmaf(p1.x,vv.z,acc[4].z); acc[4].w=fmaf(p1.x,vv.w,acc[4].w);
            acc[5].x=fmaf(p1.y,vv.x,acc[5].x); acc[5].y=fmaf(p1.y,vv.y,acc[5].y);
            acc[5].z=fmaf(p1.y,vv.z,acc[5].z); acc[5].w=fmaf(p1.y,vv.w,acc[5].w);
            acc[6].x=fmaf(p1.z,vv.x,acc[6].x); acc[6].y=fmaf(p1.z,vv.y,acc[6].y);
            acc[6].z=fmaf(p1.z,vv.z,acc[6].z); acc[6].w=fmaf(p1.z,vv.w,acc[6].w);
            acc[7].x=fmaf(p1.w,vv.x,acc[7].x); acc[7].y=fmaf(p1.w,vv.y,acc[7].y);
            acc[7].z=fmaf(p1.w,vv.z,acc[7].z); acc[7].w=fmaf(p1.w,vv.w,acc[7].w);
        }
        #pragma unroll
        for (int t = 0; t < TT; ++t)
            *(float4*)&partial[g][t][hs*4] = acc[t];
    }
    __syncthreads();

    // --- reduce 8 partials, write block result ---
    for (int i = tid; i < TT*HH; i += 256) {
        float r = 0.f;
        #pragma unroll
        for (int g = 0; g < 8; ++g) r += partial[g][i>>7][i&127];
        repp[bx*(TT*HH) + i] = r;
    }
}

// ------------- combine halves + output projection ----------------------------
__global__ __launch_bounds__(256) void combine_proj_kernel(
    const float* __restrict__ repp, const float* __restrict__ ml,
    const float* __restrict__ W_tgt, const float* __restrict__ b_tgt,
    float* __restrict__ out)
{
    const int cx  = blockIdx.x;      // 0..255 = b*64 + tb
    const int b   = cx >> 6, tb = cx & 63;
    const int t0  = tb * TT;
    const int tid = threadIdx.x;

    __shared__ float rep[TT][HH];    // 4 KB
    __shared__ float cf[NSPLIT][TT];

    if (tid < TT) {
        float mj[NSPLIT], lj[NSPLIT], aj[NSPLIT];
        float M = -1e30f;
        #pragma unroll
        for (int j = 0; j < NSPLIT; ++j) {
            mj[j] = ml[(cx*NSPLIT + j)*16 + tid];
            lj[j] = ml[(cx*NSPLIT + j)*16 + 8 + tid];
            M = fmaxf(M, mj[j]);
        }
        float L = 0.f;
        #pragma unroll
        for (int j = 0; j < NSPLIT; ++j) { aj[j] = __expf(mj[j]-M); L = fmaf(aj[j], lj[j], L); }
        float invL = 1.f / L;
        #pragma unroll
        for (int j = 0; j < NSPLIT; ++j) cf[j][tid] = aj[j] * invL;
    }
    __syncthreads();
    for (int i = tid; i < TT*HH; i += 256) {
        const int t = i >> 7;
        float acc = 0.f;
        #pragma unroll
        for (int j = 0; j < NSPLIT; ++j)
            acc = fmaf(cf[j][t], repp[(cx*NSPLIT + j)*(TT*HH) + i], acc);
        (&rep[0][0])[i] = acc;
    }
    __syncthreads();

    const int g = tid >> 7, h = tid & 127;   // g: t-quad
    float bt = b_tgt[h];
    float acc[4];
    #pragma unroll
    for (int i = 0; i < 4; ++i) acc[i] = bt;
    for (int k = 0; k < HH; k += 4) {
        float w0 = W_tgt[(k+0)*HH + h];
        float w1 = W_tgt[(k+1)*HH + h];
        float w2 = W_tgt[(k+2)*HH + h];
        float w3 = W_tgt[(k+3)*HH + h];
        #pragma unroll
        for (int i = 0; i < 4; ++i) {
            const float4 rv = *(const float4*)&rep[g*4 + i][k];
            acc[i] = fmaf(rv.x, w0, fmaf(rv.y, w1, fmaf(rv.z, w2, fmaf(rv.w, w3, acc[i]))));
        }
    }
    #pragma unroll
    for (int i = 0; i < 4; ++i)
        out[(b*TDIM + t0 + g*4 + i)*HH + h] = acc[i];
}

extern "C" void kernel_launch(void* const* d_in, const int* in_sizes, int n_in,
                              void* d_out, int out_size, void* d_ws, size_t ws_size,
                              hipStream_t stream) {
    const float* ctx_x = (const float*)d_in[0];
    const float* ctx_y = (const float*)d_in[1];
    const float* tgt_x = (const float*)d_in[2];
    const float* W_in  = (const float*)d_in[3];
    const float* b_in  = (const float*)d_in[4];
    const float* W_ctx = (const float*)d_in[5];
    const float* b_ctx = (const float*)d_in[6];
    const float* W_tgt = (const float*)d_in[7];
    const float* b_tgt = (const float*)d_in[8];

    float* ws    = (float*)d_ws;
    float* key   = ws;                      // 262144 f32
    float* query = ws + 1*BB*CC*HH;         // 262144
    float* value = ws + 2*BB*CC*HH;         // 262144
    float* repp  = ws + 3*BB*CC*HH;         // 512 blocks * 1024
    float* ml    = repp + 512*TT*HH;        // 512 blocks * 16

    prep_kernel<<<BB*CC, 128, 0, stream>>>(ctx_x, ctx_y, tgt_x,
                                           W_in, b_in, W_ctx, b_ctx,
                                           key, query, value);
    score_pv_kernel<<<BB*(TDIM/TT)*NSPLIT, 256, 0, stream>>>(key, query, value,
                                                             repp, ml);
    combine_proj_kernel<<<BB*(TDIM/TT), 256, 0, stream>>>(repp, ml, W_tgt, b_tgt,
                                                          (float*)d_out);
}